// Round 5
// baseline (1001.947 us; speedup 1.0000x reference)
//
#include <hip/hip_runtime.h>

#define BB 32
#define NN 4096
#define CC 768
#define HH 12
#define DD 64
#define QSCALE 0.125f

// ws layout (floats)
#define OFF_Q       0           // [B][H][D]          24576
#define OFF_SB      24576       // [B][H]             384
#define OFF_U       24960       // [B][H][C]          294912
#define OFF_WPART   319872      // [B][16][H][C]      4718592
#define OFF_XCLSPRE 5038464     // [B][C]             24576
// total 5063040 floats = 20.25 MB

// ---------------------------------------------------------------------------
// K1: q[b,h,d] = (x[b,0,:] @ Wq[:,h*64+d] + bq) * SCALE
// block 256 = 64 d-lanes x 4 c-groups, LDS reduce
__global__ __launch_bounds__(256) void k_q(const float* __restrict__ x,
                                           const float* __restrict__ Wq,
                                           const float* __restrict__ bq,
                                           float* __restrict__ q) {
    int bh = blockIdx.x;
    int b = bh / HH, h = bh % HH;
    int t = threadIdx.x;
    int d = t & 63, cg = t >> 6;
    int col = h * DD + d;
    const float* xr = x + (size_t)b * NN * CC;   // row n=0
    float acc = 0.f;
    #pragma unroll 8
    for (int c = cg * 192; c < cg * 192 + 192; ++c)
        acc += xr[c] * Wq[(size_t)c * CC + col];
    __shared__ float red[256];
    red[t] = acc;
    __syncthreads();
    if (t < 64) {
        float v = red[t] + red[t + 64] + red[t + 128] + red[t + 192];
        q[bh * DD + d] = (v + bq[col]) * QSCALE;
    }
}

// ---------------------------------------------------------------------------
// K2: U[b,h,c] = sum_d Wk[c, h*64+d] * q[b,h,d];  sb[b,h] = q . bk[h-slice]
__global__ __launch_bounds__(256) void k_U(const float* __restrict__ Wk,
                                           const float* __restrict__ bk,
                                           const float* __restrict__ q,
                                           float* __restrict__ U,
                                           float* __restrict__ sb) {
    int bh = blockIdx.x;
    int h = bh % HH;
    __shared__ float qs[DD];
    int t = threadIdx.x;
    if (t < DD) qs[t] = q[bh * DD + t];
    __syncthreads();
    for (int c = t; c < CC; c += 256) {
        const float4* wr = (const float4*)(Wk + (size_t)c * CC + h * DD);
        float acc = 0.f;
        #pragma unroll
        for (int d4 = 0; d4 < DD / 4; ++d4) {
            float4 wv = wr[d4];
            acc += wv.x * qs[4 * d4] + wv.y * qs[4 * d4 + 1]
                 + wv.z * qs[4 * d4 + 2] + wv.w * qs[4 * d4 + 3];
        }
        U[(size_t)bh * CC + c] = acc;
    }
    if (t == 0) {
        float acc = 0.f;
        for (int d = 0; d < DD; ++d) acc += qs[d] * bk[h * DD + d];
        sb[bh] = acc;
    }
}

// ---------------------------------------------------------------------------
// K3: scores[b,h,n] = x[b,n,:] . U[b,h,:] + sb[b,h]   (written to attn region)
// grid 32b x 32chunks(128 rows); block 256 = 4 waves; wave handles 2 rows/iter
__global__ __launch_bounds__(256) void k_scores(const float* __restrict__ x,
                                                const float* __restrict__ U,
                                                const float* __restrict__ sb,
                                                float* __restrict__ scores) {
    int b = blockIdx.x >> 5, chunk = blockIdx.x & 31;
    int n0 = chunk * 128;
    __shared__ float4 U4[HH * 192];   // 36 KB
    __shared__ float sbs[HH];
    int t = threadIdx.x;
    const float4* Ug = (const float4*)(U + (size_t)b * HH * CC);
    for (int i = t; i < HH * 192; i += 256) U4[i] = Ug[i];
    if (t < HH) sbs[t] = sb[b * HH + t];
    __syncthreads();
    int w = t >> 6, l = t & 63;
    for (int i = 0; i < 16; ++i) {
        int n = n0 + i * 8 + w * 2;
        const float4* xr0 = (const float4*)(x + ((size_t)b * NN + n) * CC);
        const float4* xr1 = xr0 + 192;
        float4 a0[3], a1[3];
        a0[0] = xr0[l]; a0[1] = xr0[l + 64]; a0[2] = xr0[l + 128];
        a1[0] = xr1[l]; a1[1] = xr1[l + 64]; a1[2] = xr1[l + 128];
        float acc0[HH], acc1[HH];
        #pragma unroll
        for (int h = 0; h < HH; ++h) { acc0[h] = 0.f; acc1[h] = 0.f; }
        #pragma unroll
        for (int k = 0; k < 3; ++k) {
            #pragma unroll
            for (int h = 0; h < HH; ++h) {
                float4 u = U4[h * 192 + k * 64 + l];
                acc0[h] += u.x * a0[k].x + u.y * a0[k].y + u.z * a0[k].z + u.w * a0[k].w;
                acc1[h] += u.x * a1[k].x + u.y * a1[k].y + u.z * a1[k].z + u.w * a1[k].w;
            }
        }
        #pragma unroll
        for (int h = 0; h < HH; ++h) {
            float v0 = acc0[h], v1 = acc1[h];
            #pragma unroll
            for (int m = 32; m; m >>= 1) {
                v0 += __shfl_xor(v0, m, 64);
                v1 += __shfl_xor(v1, m, 64);
            }
            acc0[h] = v0; acc1[h] = v1;
        }
        float out0 = 0.f, out1 = 0.f;
        #pragma unroll
        for (int h = 0; h < HH; ++h) {
            if (l == h) { out0 = acc0[h]; out1 = acc1[h]; }
        }
        if (l < HH) {
            scores[((size_t)b * HH + l) * NN + n]     = out0 + sbs[l];
            scores[((size_t)b * HH + l) * NN + n + 1] = out1 + sbs[l];
        }
    }
}

// ---------------------------------------------------------------------------
// K4: in-place softmax over each row of attn[b*H+h][0..N)
__global__ __launch_bounds__(256) void k_softmax(float* __restrict__ attn) {
    int bh = blockIdx.x;
    float4* row = (float4*)(attn + (size_t)bh * NN);
    int t = threadIdx.x;
    float4 v[4];
    #pragma unroll
    for (int i = 0; i < 4; ++i) v[i] = row[t + 256 * i];
    float m = -1e30f;
    #pragma unroll
    for (int i = 0; i < 4; ++i)
        m = fmaxf(m, fmaxf(fmaxf(v[i].x, v[i].y), fmaxf(v[i].z, v[i].w)));
    #pragma unroll
    for (int mm = 32; mm; mm >>= 1) m = fmaxf(m, __shfl_xor(m, mm, 64));
    __shared__ float redm[4], reds[4];
    int w = t >> 6, l = t & 63;
    if (l == 0) redm[w] = m;
    __syncthreads();
    m = fmaxf(fmaxf(redm[0], redm[1]), fmaxf(redm[2], redm[3]));
    float s = 0.f;
    #pragma unroll
    for (int i = 0; i < 4; ++i) {
        v[i].x = __expf(v[i].x - m); v[i].y = __expf(v[i].y - m);
        v[i].z = __expf(v[i].z - m); v[i].w = __expf(v[i].w - m);
        s += v[i].x + v[i].y + v[i].z + v[i].w;
    }
    #pragma unroll
    for (int mm = 32; mm; mm >>= 1) s += __shfl_xor(s, mm, 64);
    if (l == 0) reds[w] = s;
    __syncthreads();
    float inv = 1.f / (reds[0] + reds[1] + reds[2] + reds[3]);
    #pragma unroll
    for (int i = 0; i < 4; ++i) {
        v[i].x *= inv; v[i].y *= inv; v[i].z *= inv; v[i].w *= inv;
        row[t + 256 * i] = v[i];
    }
}

// ---------------------------------------------------------------------------
// K5: wpart[b,chunk,h,c] = sum_{n in chunk} attn[b,h,n] * x[b,n,c]
// grid 32b x 16chunks(256 rows); block 256 = 4 waves; wave w owns h in {3w..3w+2}
#define FMA4(A, s, X) { (A).x += (s)*(X).x; (A).y += (s)*(X).y; (A).z += (s)*(X).z; (A).w += (s)*(X).w; }
__global__ __launch_bounds__(256) void k_wpart(const float* __restrict__ x,
                                               const float* __restrict__ attn,
                                               float* __restrict__ wpart) {
    int b = blockIdx.x >> 4, chunk = blockIdx.x & 15;
    int n0 = chunk * 256;
    __shared__ float al[HH][256];   // 12 KB
    int t = threadIdx.x;
    const float* ag = attn + (size_t)b * HH * NN + n0;
    for (int i = t; i < HH * 64; i += 256) {   // 768 float4 items
        int h = i >> 6, p = i & 63;
        ((float4*)&al[h][0])[p] = ((const float4*)(ag + (size_t)h * NN))[p];
    }
    __syncthreads();
    int w = t >> 6, l = t & 63;
    int h0 = 3 * w;
    float4 acc[3][3];
    #pragma unroll
    for (int j = 0; j < 3; ++j)
        #pragma unroll
        for (int k = 0; k < 3; ++k)
            acc[j][k] = make_float4(0.f, 0.f, 0.f, 0.f);
    const float4* xb = (const float4*)(x + ((size_t)b * NN + n0) * CC);
    #pragma unroll 4
    for (int i = 0; i < 256; ++i) {
        const float4* xr = xb + (size_t)i * 192;
        float4 x0 = xr[l], x1 = xr[l + 64], x2 = xr[l + 128];
        float a0 = al[h0][i], a1 = al[h0 + 1][i], a2 = al[h0 + 2][i];
        FMA4(acc[0][0], a0, x0); FMA4(acc[0][1], a0, x1); FMA4(acc[0][2], a0, x2);
        FMA4(acc[1][0], a1, x0); FMA4(acc[1][1], a1, x1); FMA4(acc[1][2], a1, x2);
        FMA4(acc[2][0], a2, x0); FMA4(acc[2][1], a2, x1); FMA4(acc[2][2], a2, x2);
    }
    float* wp = wpart + (((size_t)b * 16 + chunk) * HH) * CC;
    #pragma unroll
    for (int j = 0; j < 3; ++j) {
        float4* wr = (float4*)(wp + (h0 + j) * CC);
        #pragma unroll
        for (int k = 0; k < 3; ++k) wr[l + 64 * k] = acc[j][k];
    }
}

// ---------------------------------------------------------------------------
// K6: w[b,h,c] = sum_chunk wpart; xclspre[b, h*64+d] = w . Wv[:, h*64+d] + bv
__global__ __launch_bounds__(256) void k_xcls1(const float* __restrict__ wpart,
                                               const float* __restrict__ Wv,
                                               const float* __restrict__ bv,
                                               float* __restrict__ xclspre) {
    int bh = blockIdx.x, b = bh / HH, h = bh % HH;
    __shared__ float wl[CC];
    __shared__ float red[256];
    int t = threadIdx.x;
    for (int c = t; c < CC; c += 256) {
        float s = 0.f;
        #pragma unroll
        for (int ch = 0; ch < 16; ++ch)
            s += wpart[(((size_t)b * 16 + ch) * HH + h) * CC + c];
        wl[c] = s;
    }
    __syncthreads();
    int d = t & 63, cg = t >> 6;
    int col = h * DD + d;
    float acc = 0.f;
    #pragma unroll 8
    for (int c = cg * 192; c < cg * 192 + 192; ++c)
        acc += wl[c] * Wv[(size_t)c * CC + col];
    red[t] = acc;
    __syncthreads();
    if (t < 64)
        xclspre[b * CC + col] = red[t] + red[t + 64] + red[t + 128] + red[t + 192] + bv[col];
}

// ---------------------------------------------------------------------------
// K7: out[b,j] = xclspre[b,:] @ Wp[:,j] + bp[j]
__global__ __launch_bounds__(256) void k_proj(const float* __restrict__ xclspre,
                                              const float* __restrict__ Wp,
                                              const float* __restrict__ bp,
                                              float* __restrict__ out) {
    int blk = blockIdx.x, b = blk / 12, jg = blk % 12;
    __shared__ float xs[CC];
    __shared__ float red[256];
    int t = threadIdx.x;
    for (int c = t; c < CC; c += 256) xs[c] = xclspre[b * CC + c];
    __syncthreads();
    int d = t & 63, cg = t >> 6;
    int j = jg * DD + d;
    float acc = 0.f;
    #pragma unroll 8
    for (int c = cg * 192; c < cg * 192 + 192; ++c)
        acc += xs[c] * Wp[(size_t)c * CC + j];
    red[t] = acc;
    __syncthreads();
    if (t < 64)
        out[b * CC + j] = red[t] + red[t + 64] + red[t + 128] + red[t + 192] + bp[j];
}

// ---------------------------------------------------------------------------
extern "C" void kernel_launch(void* const* d_in, const int* in_sizes, int n_in,
                              void* d_out, int out_size, void* d_ws, size_t ws_size,
                              hipStream_t stream) {
    const float* x  = (const float*)d_in[0];
    const float* Wq = (const float*)d_in[1];
    const float* bq = (const float*)d_in[2];
    const float* Wk = (const float*)d_in[3];
    const float* bk = (const float*)d_in[4];
    const float* Wv = (const float*)d_in[5];
    const float* bv = (const float*)d_in[6];
    const float* Wp = (const float*)d_in[7];
    const float* bp = (const float*)d_in[8];
    float* out = (float*)d_out;
    float* ws  = (float*)d_ws;

    float* q       = ws + OFF_Q;
    float* sb      = ws + OFF_SB;
    float* U       = ws + OFF_U;
    float* wpart   = ws + OFF_WPART;
    float* xclspre = ws + OFF_XCLSPRE;

    float* xcls = out;              // [B][C]
    float* attn = out + BB * CC;    // [B][H][N] — scores written here, softmaxed in place

    hipLaunchKernelGGL(k_q,       dim3(BB * HH), dim3(256), 0, stream, x, Wq, bq, q);
    hipLaunchKernelGGL(k_U,       dim3(BB * HH), dim3(256), 0, stream, Wk, bk, q, U, sb);
    hipLaunchKernelGGL(k_scores,  dim3(BB * 32), dim3(256), 0, stream, x, U, sb, attn);
    hipLaunchKernelGGL(k_softmax, dim3(BB * HH), dim3(256), 0, stream, attn);
    hipLaunchKernelGGL(k_wpart,   dim3(BB * 16), dim3(256), 0, stream, x, attn, wpart);
    hipLaunchKernelGGL(k_xcls1,   dim3(BB * HH), dim3(256), 0, stream, wpart, Wv, bv, xclspre);
    hipLaunchKernelGGL(k_proj,    dim3(BB * 12), dim3(256), 0, stream, xclspre, Wp, bp, xcls);
}

// Round 6
// 702.019 us; speedup vs baseline: 1.4272x; 1.4272x over previous
//
#include <hip/hip_runtime.h>

#define BB 32
#define NN 4096
#define CC 768
#define HH 12
#define DD 64
#define QSCALE 0.125f
#define NCHUNK 32            // chunks for wpart (128 rows each)

// ws layout (floats)
#define OFF_Q       0           // [B][H][D]            24576
#define OFF_SB      24576       // [B][H]               384
#define OFF_U       24960       // [B][H][C]            294912
#define OFF_WPART   319872      // [B][32][H][C]        9437184
#define OFF_XCLSPRE 9757056     // [B][C]               24576
// total 9781632 floats = 39.1 MB

// ---------------------------------------------------------------------------
// K1: q[b,h,d] = (x[b,0,:] @ Wq[:,h*64+d] + bq) * SCALE
__global__ __launch_bounds__(256) void k_q(const float* __restrict__ x,
                                           const float* __restrict__ Wq,
                                           const float* __restrict__ bq,
                                           float* __restrict__ q) {
    int bh = blockIdx.x;
    int b = bh / HH, h = bh % HH;
    int t = threadIdx.x;
    int d = t & 63, cg = t >> 6;
    int col = h * DD + d;
    const float* xr = x + (size_t)b * NN * CC;   // row n=0
    float acc = 0.f;
    #pragma unroll 8
    for (int c = cg * 192; c < cg * 192 + 192; ++c)
        acc += xr[c] * Wq[(size_t)c * CC + col];
    __shared__ float red[256];
    red[t] = acc;
    __syncthreads();
    if (t < 64) {
        float v = red[t] + red[t + 64] + red[t + 128] + red[t + 192];
        q[bh * DD + d] = (v + bq[col]) * QSCALE;
    }
}

// ---------------------------------------------------------------------------
// K2: U[b,h,c] = sum_d Wk[c, h*64+d] * q[b,h,d];  sb[b,h] = q . bk[h-slice]
__global__ __launch_bounds__(256) void k_U(const float* __restrict__ Wk,
                                           const float* __restrict__ bk,
                                           const float* __restrict__ q,
                                           float* __restrict__ U,
                                           float* __restrict__ sb) {
    int bh = blockIdx.x;
    int h = bh % HH;
    __shared__ float qs[DD];
    int t = threadIdx.x;
    if (t < DD) qs[t] = q[bh * DD + t];
    __syncthreads();
    for (int c = t; c < CC; c += 256) {
        const float4* wr = (const float4*)(Wk + (size_t)c * CC + h * DD);
        float acc = 0.f;
        #pragma unroll
        for (int d4 = 0; d4 < DD / 4; ++d4) {
            float4 wv = wr[d4];
            acc += wv.x * qs[4 * d4] + wv.y * qs[4 * d4 + 1]
                 + wv.z * qs[4 * d4 + 2] + wv.w * qs[4 * d4 + 3];
        }
        U[(size_t)bh * CC + c] = acc;
    }
    if (t == 0) {
        float acc = 0.f;
        for (int d = 0; d < DD; ++d) acc += qs[d] * bk[h * DD + d];
        sb[bh] = acc;
    }
}

// ---------------------------------------------------------------------------
// K3: scores[b,h,n] = x[b,n,:] . U[b,h,:] + sb[b,h]
// grid 32b x 32chunks(128 rows); block 512 = 8 waves; each wave 1 row/iter, 16 iters
__global__ __launch_bounds__(512) void k_scores(const float* __restrict__ x,
                                                const float* __restrict__ U,
                                                const float* __restrict__ sb,
                                                float* __restrict__ scores) {
    int b = blockIdx.x >> 5, chunk = blockIdx.x & 31;
    int n0 = chunk * 128;
    __shared__ float4 U4[HH * 192];   // 36 KB
    __shared__ float sbs[HH];
    int t = threadIdx.x;
    const float4* Ug = (const float4*)(U + (size_t)b * HH * CC);
    for (int i = t; i < HH * 192; i += 512) U4[i] = Ug[i];
    if (t < HH) sbs[t] = sb[b * HH + t];
    __syncthreads();
    int w = t >> 6, l = t & 63;
    #pragma unroll 2
    for (int i = 0; i < 16; ++i) {
        int n = n0 + i * 8 + w;
        const float4* xr = (const float4*)(x + ((size_t)b * NN + n) * CC);
        float4 a0 = xr[l], a1 = xr[l + 64], a2 = xr[l + 128];
        float acc[HH];
        #pragma unroll
        for (int h = 0; h < HH; ++h) {
            float4 u0 = U4[h * 192 + l];
            float4 u1 = U4[h * 192 + 64 + l];
            float4 u2 = U4[h * 192 + 128 + l];
            acc[h] = a0.x * u0.x + a0.y * u0.y + a0.z * u0.z + a0.w * u0.w
                   + a1.x * u1.x + a1.y * u1.y + a1.z * u1.z + a1.w * u1.w
                   + a2.x * u2.x + a2.y * u2.y + a2.z * u2.z + a2.w * u2.w;
        }
        #pragma unroll
        for (int h = 0; h < HH; ++h) {
            float v = acc[h];
            #pragma unroll
            for (int m = 32; m; m >>= 1) v += __shfl_xor(v, m, 64);
            acc[h] = v;
        }
        float outv = 0.f;
        #pragma unroll
        for (int h = 0; h < HH; ++h)
            if (l == h) outv = acc[h];      // compile-time index into acc (rule #20)
        if (l < HH)
            scores[((size_t)b * HH + l) * NN + n] = outv + sbs[l];
    }
}

// ---------------------------------------------------------------------------
// K4: in-place softmax over each row of attn[b*H+h][0..N)
__global__ __launch_bounds__(256) void k_softmax(float* __restrict__ attn) {
    int bh = blockIdx.x;
    float4* row = (float4*)(attn + (size_t)bh * NN);
    int t = threadIdx.x;
    float4 v[4];
    #pragma unroll
    for (int i = 0; i < 4; ++i) v[i] = row[t + 256 * i];
    float m = -1e30f;
    #pragma unroll
    for (int i = 0; i < 4; ++i)
        m = fmaxf(m, fmaxf(fmaxf(v[i].x, v[i].y), fmaxf(v[i].z, v[i].w)));
    #pragma unroll
    for (int mm = 32; mm; mm >>= 1) m = fmaxf(m, __shfl_xor(m, mm, 64));
    __shared__ float redm[4], reds[4];
    int w = t >> 6, l = t & 63;
    if (l == 0) redm[w] = m;
    __syncthreads();
    m = fmaxf(fmaxf(redm[0], redm[1]), fmaxf(redm[2], redm[3]));
    float s = 0.f;
    #pragma unroll
    for (int i = 0; i < 4; ++i) {
        v[i].x = __expf(v[i].x - m); v[i].y = __expf(v[i].y - m);
        v[i].z = __expf(v[i].z - m); v[i].w = __expf(v[i].w - m);
        s += v[i].x + v[i].y + v[i].z + v[i].w;
    }
    #pragma unroll
    for (int mm = 32; mm; mm >>= 1) s += __shfl_xor(s, mm, 64);
    if (l == 0) reds[w] = s;
    __syncthreads();
    float inv = 1.f / (reds[0] + reds[1] + reds[2] + reds[3]);
    #pragma unroll
    for (int i = 0; i < 4; ++i) {
        v[i].x *= inv; v[i].y *= inv; v[i].z *= inv; v[i].w *= inv;
        row[t + 256 * i] = v[i];
    }
}

// ---------------------------------------------------------------------------
// K5 v2: wpart[b,chunk,h,c] = sum_{n in chunk(128)} attn[b,h,n] * x[b,n,c]
// grid 32b x 32chunks; block 192 threads (3 waves). Thread t owns float4 column t;
// iterates all 128 rows -> x loaded EXACTLY ONCE block-wide (no cross-wave redundancy).
#define FMA4(A, s, X) { (A).x += (s)*(X).x; (A).y += (s)*(X).y; (A).z += (s)*(X).z; (A).w += (s)*(X).w; }
__global__ __launch_bounds__(192) void k_wpart(const float* __restrict__ x,
                                               const float* __restrict__ attn,
                                               float* __restrict__ wpart) {
    int b = blockIdx.x >> 5, chunk = blockIdx.x & 31;
    int n0 = chunk * 128;
    __shared__ float al[128][HH];   // [n][h], 6 KB; rows are 48B -> float4-aligned
    int t = threadIdx.x;            // 0..191
    const float* ag = attn + (size_t)b * HH * NN + n0;
    for (int i = t; i < HH * 128; i += 192) {
        int h = i >> 7, n = i & 127;
        al[n][h] = ag[(size_t)h * NN + n];
    }
    __syncthreads();
    float4 acc[HH];
    #pragma unroll
    for (int h = 0; h < HH; ++h) acc[h] = make_float4(0.f, 0.f, 0.f, 0.f);
    const float4* xb = (const float4*)(x + ((size_t)b * NN + n0) * CC);
    #pragma unroll 4
    for (int n = 0; n < 128; ++n) {
        float4 xv = xb[(size_t)n * 192 + t];
        float4 a0 = *(const float4*)&al[n][0];   // heads 0..3  (LDS broadcast)
        float4 a1 = *(const float4*)&al[n][4];   // heads 4..7
        float4 a2 = *(const float4*)&al[n][8];   // heads 8..11
        FMA4(acc[0],  a0.x, xv); FMA4(acc[1],  a0.y, xv);
        FMA4(acc[2],  a0.z, xv); FMA4(acc[3],  a0.w, xv);
        FMA4(acc[4],  a1.x, xv); FMA4(acc[5],  a1.y, xv);
        FMA4(acc[6],  a1.z, xv); FMA4(acc[7],  a1.w, xv);
        FMA4(acc[8],  a2.x, xv); FMA4(acc[9],  a2.y, xv);
        FMA4(acc[10], a2.z, xv); FMA4(acc[11], a2.w, xv);
    }
    float4* wp = (float4*)(wpart + (((size_t)b * NCHUNK + chunk) * HH) * CC);
    #pragma unroll
    for (int h = 0; h < HH; ++h)
        wp[h * 192 + t] = acc[h];
}

// ---------------------------------------------------------------------------
// K6: w[b,h,c] = sum_chunk wpart; xclspre[b, h*64+d] = w . Wv[:, h*64+d] + bv
__global__ __launch_bounds__(256) void k_xcls1(const float* __restrict__ wpart,
                                               const float* __restrict__ Wv,
                                               const float* __restrict__ bv,
                                               float* __restrict__ xclspre) {
    int bh = blockIdx.x, b = bh / HH, h = bh % HH;
    __shared__ float wl[CC];
    __shared__ float red[256];
    int t = threadIdx.x;
    for (int c = t; c < CC; c += 256) {
        float s = 0.f;
        #pragma unroll
        for (int ch = 0; ch < NCHUNK; ++ch)
            s += wpart[(((size_t)b * NCHUNK + ch) * HH + h) * CC + c];
        wl[c] = s;
    }
    __syncthreads();
    int d = t & 63, cg = t >> 6;
    int col = h * DD + d;
    float acc = 0.f;
    #pragma unroll 8
    for (int c = cg * 192; c < cg * 192 + 192; ++c)
        acc += wl[c] * Wv[(size_t)c * CC + col];
    red[t] = acc;
    __syncthreads();
    if (t < 64)
        xclspre[b * CC + col] = red[t] + red[t + 64] + red[t + 128] + red[t + 192] + bv[col];
}

// ---------------------------------------------------------------------------
// K7: out[b,j] = xclspre[b,:] @ Wp[:,j] + bp[j]
__global__ __launch_bounds__(256) void k_proj(const float* __restrict__ xclspre,
                                              const float* __restrict__ Wp,
                                              const float* __restrict__ bp,
                                              float* __restrict__ out) {
    int blk = blockIdx.x, b = blk / 12, jg = blk % 12;
    __shared__ float xs[CC];
    __shared__ float red[256];
    int t = threadIdx.x;
    for (int c = t; c < CC; c += 256) xs[c] = xclspre[b * CC + c];
    __syncthreads();
    int d = t & 63, cg = t >> 6;
    int j = jg * DD + d;
    float acc = 0.f;
    #pragma unroll 8
    for (int c = cg * 192; c < cg * 192 + 192; ++c)
        acc += xs[c] * Wp[(size_t)c * CC + j];
    red[t] = acc;
    __syncthreads();
    if (t < 64)
        out[b * CC + j] = red[t] + red[t + 64] + red[t + 128] + red[t + 192] + bp[j];
}

// ---------------------------------------------------------------------------
extern "C" void kernel_launch(void* const* d_in, const int* in_sizes, int n_in,
                              void* d_out, int out_size, void* d_ws, size_t ws_size,
                              hipStream_t stream) {
    const float* x  = (const float*)d_in[0];
    const float* Wq = (const float*)d_in[1];
    const float* bq = (const float*)d_in[2];
    const float* Wk = (const float*)d_in[3];
    const float* bk = (const float*)d_in[4];
    const float* Wv = (const float*)d_in[5];
    const float* bv = (const float*)d_in[6];
    const float* Wp = (const float*)d_in[7];
    const float* bp = (const float*)d_in[8];
    float* out = (float*)d_out;
    float* ws  = (float*)d_ws;

    float* q       = ws + OFF_Q;
    float* sb      = ws + OFF_SB;
    float* U       = ws + OFF_U;
    float* wpart   = ws + OFF_WPART;
    float* xclspre = ws + OFF_XCLSPRE;

    float* xcls = out;              // [B][C]
    float* attn = out + BB * CC;    // [B][H][N] — scores written here, softmaxed in place

    hipLaunchKernelGGL(k_q,       dim3(BB * HH), dim3(256), 0, stream, x, Wq, bq, q);
    hipLaunchKernelGGL(k_U,       dim3(BB * HH), dim3(256), 0, stream, Wk, bk, q, U, sb);
    hipLaunchKernelGGL(k_scores,  dim3(BB * 32), dim3(512), 0, stream, x, U, sb, attn);
    hipLaunchKernelGGL(k_softmax, dim3(BB * HH), dim3(256), 0, stream, attn);
    hipLaunchKernelGGL(k_wpart,   dim3(BB * NCHUNK), dim3(192), 0, stream, x, attn, wpart);
    hipLaunchKernelGGL(k_xcls1,   dim3(BB * HH), dim3(256), 0, stream, wpart, Wv, bv, xclspre);
    hipLaunchKernelGGL(k_proj,    dim3(BB * 12), dim3(256), 0, stream, xclspre, Wp, bp, xcls);
}